// Round 1
// baseline (24.662 us; speedup 1.0000x reference)
//
#include <hip/hip_runtime.h>
#include <hip/hip_bf16.h>
#include <stdint.h>

#define DIM 1024
#define BATCH 128
#define EPS_BN 1e-5f

typedef __attribute__((ext_vector_type(8))) short bfrag;   // 8 bf16 (4 VGPRs)
typedef __attribute__((ext_vector_type(4))) float f32x4;   // MFMA accumulator

__device__ inline ushort f2bf(float f) {
    union { float f; uint32_t u; } un; un.f = f;
    uint32_t u = un.u;
    return (ushort)((u + 0x7FFFu + ((u >> 16) & 1u)) >> 16);  // RNE
}

// ---------------------------------------------------------------------------
// K1: q,k,v = z @ W.T  (three 128x1024x1024 GEMMs, treated as N=3072)
// C[b,n] = sum_d z[b,d] * W[n,d].  Tile: BM=32, BN=64, BK=64. 192 blocks.
// ---------------------------------------------------------------------------
__global__ __launch_bounds__(256) void qkv_gemm(
    const float* __restrict__ z, const float* __restrict__ Wq,
    const float* __restrict__ Wk, const float* __restrict__ Wv,
    float* __restrict__ qkv)
{
    // +8 bf16 pad -> 144B row stride (16B aligned, breaks 128B bank cycling)
    __shared__ alignas(16) ushort As[32][72];
    __shared__ alignas(16) ushort Bs[64][72];

    const int bid = blockIdx.x;
    const int nt = bid % 48, mt = bid / 48;
    const int m0 = mt * 32;
    const int n0 = nt * 64;
    const int w_idx = n0 >> 10;                 // which W (tile never crosses)
    const float* W = (w_idx == 0) ? Wq : (w_idx == 1) ? Wk : Wv;
    const int nrow0 = n0 & 1023;

    const int t = threadIdx.x;
    const int lane = t & 63, wv = t >> 6;
    const int wm = wv >> 1, wn = wv & 1;

    // staging assignments
    const int ar = t >> 3, ac = (t & 7) * 8;    // A tile [32][64]
    const int br = t >> 2, bc = (t & 3) * 16;   // B tile [64][64]
    const float* zrow = z + (size_t)(m0 + ar) * DIM + ac;
    const float* wrow = W + (size_t)(nrow0 + br) * DIM + bc;

    f32x4 acc[2] = {{0.f,0.f,0.f,0.f},{0.f,0.f,0.f,0.f}};

    for (int kk = 0; kk < DIM; kk += 64) {
        // stage A: 8 f32 -> 8 bf16
        {
            float4 f0 = *(const float4*)(zrow + kk);
            float4 f1 = *(const float4*)(zrow + kk + 4);
            ushort tmp[8] = { f2bf(f0.x), f2bf(f0.y), f2bf(f0.z), f2bf(f0.w),
                              f2bf(f1.x), f2bf(f1.y), f2bf(f1.z), f2bf(f1.w) };
            *(bfrag*)&As[ar][ac] = *(bfrag*)tmp;
        }
        // stage B: 16 f32 -> 16 bf16
        {
            float4 f0 = *(const float4*)(wrow + kk);
            float4 f1 = *(const float4*)(wrow + kk + 4);
            float4 f2 = *(const float4*)(wrow + kk + 8);
            float4 f3 = *(const float4*)(wrow + kk + 12);
            ushort tmp[16] = { f2bf(f0.x), f2bf(f0.y), f2bf(f0.z), f2bf(f0.w),
                               f2bf(f1.x), f2bf(f1.y), f2bf(f1.z), f2bf(f1.w),
                               f2bf(f2.x), f2bf(f2.y), f2bf(f2.z), f2bf(f2.w),
                               f2bf(f3.x), f2bf(f3.y), f2bf(f3.z), f2bf(f3.w) };
            *(bfrag*)&Bs[br][bc]     = *(bfrag*)&tmp[0];
            *(bfrag*)&Bs[br][bc + 8] = *(bfrag*)&tmp[8];
        }
        __syncthreads();

        const int krow = (lane >> 4) * 8;  // this lane-group's K slot (bijection, same for A and B)
        #pragma unroll
        for (int mk = 0; mk < 2; ++mk) {
            bfrag af  = *(const bfrag*)&As[wm * 16      + (lane & 15)][mk * 32 + krow];
            bfrag bf0 = *(const bfrag*)&Bs[wn * 32      + (lane & 15)][mk * 32 + krow];
            bfrag bf1 = *(const bfrag*)&Bs[wn * 32 + 16 + (lane & 15)][mk * 32 + krow];
            acc[0] = __builtin_amdgcn_mfma_f32_16x16x32_bf16(af, bf0, acc[0], 0, 0, 0);
            acc[1] = __builtin_amdgcn_mfma_f32_16x16x32_bf16(af, bf1, acc[1], 0, 0, 0);
        }
        __syncthreads();
    }

    // epilogue: C/D layout (HW-verified): col = lane&15, row = (lane>>4)*4 + reg
    float* outbase = qkv + (size_t)w_idx * (BATCH * DIM);
    #pragma unroll
    for (int fn = 0; fn < 2; ++fn) {
        const int col = nrow0 + wn * 32 + fn * 16 + (lane & 15);
        #pragma unroll
        for (int r = 0; r < 4; ++r) {
            const int row = m0 + wm * 16 + (lane >> 4) * 4 + r;
            outbase[(size_t)row * DIM + col] = acc[fn][r];
        }
    }
}

// ---------------------------------------------------------------------------
// K2: per-batch Taylor moments of exp(q_i * kn_j), then out0 = N/S + v
// ---------------------------------------------------------------------------
__global__ __launch_bounds__(256) void attn_poly(
    const float* __restrict__ qkv, float* __restrict__ out0)
{
    const int b = blockIdx.x;
    const int t = threadIdx.x;
    const float* q = qkv + (size_t)b * DIM;
    const float* k = qkv + (size_t)BATCH * DIM + (size_t)b * DIM;
    const float* v = qkv + (size_t)2 * BATCH * DIM + (size_t)b * DIM;
    const float inv_n = 0.03125f;  // 1/sqrt(1024)

    float m0[9], m1[9];
    #pragma unroll
    for (int p = 0; p < 9; ++p) { m0[p] = 0.f; m1[p] = 0.f; }
    float vv[4];
    #pragma unroll
    for (int c = 0; c < 4; ++c) {
        const int j = t + c * 256;
        const float kn = k[j] * inv_n;
        const float vj = v[j];
        vv[c] = vj;
        float pw = 1.f;
        #pragma unroll
        for (int p = 0; p < 9; ++p) { m0[p] += pw; m1[p] += pw * vj; pw *= kn; }
    }
    // wave reduce (64 lanes)
    #pragma unroll
    for (int p = 0; p < 9; ++p) {
        for (int off = 32; off; off >>= 1) {
            m0[p] += __shfl_xor(m0[p], off);
            m1[p] += __shfl_xor(m1[p], off);
        }
    }
    __shared__ float red0[4][9], red1[4][9];
    const int wv = t >> 6, lane = t & 63;
    if (lane == 0) {
        #pragma unroll
        for (int p = 0; p < 9; ++p) { red0[wv][p] = m0[p]; red1[wv][p] = m1[p]; }
    }
    __syncthreads();

    const float invfact[9] = {1.f, 1.f, 0.5f, 1.f/6.f, 1.f/24.f, 1.f/120.f,
                              1.f/720.f, 1.f/5040.f, 1.f/40320.f};
    float c0[9], c1[9];
    #pragma unroll
    for (int p = 0; p < 9; ++p) {
        const float s0 = red0[0][p] + red0[1][p] + red0[2][p] + red0[3][p];
        const float s1 = red1[0][p] + red1[1][p] + red1[2][p] + red1[3][p];
        c0[p] = s0 * invfact[p];
        c1[p] = s1 * invfact[p];
    }
    #pragma unroll
    for (int c = 0; c < 4; ++c) {
        const int i = t + c * 256;
        const float qi = q[i];
        float S = c0[8], N = c1[8];
        #pragma unroll
        for (int p = 7; p >= 0; --p) { S = S * qi + c0[p]; N = N * qi + c1[p]; }
        out0[(size_t)b * DIM + i] = N / S + vv[c];
    }
}

// ---------------------------------------------------------------------------
// K3: BatchNorm over batch axis (biased var), y = (x-mean)*rsqrt(var+eps)*g+b
// ---------------------------------------------------------------------------
__global__ __launch_bounds__(256) void batchnorm(
    const float* __restrict__ out0, const float* __restrict__ gamma,
    const float* __restrict__ beta, float* __restrict__ out)
{
    __shared__ float ls[8][32], ls2[8][32], la[32], lb[32];
    const int t = threadIdx.x;
    const int f = blockIdx.x * 32 + (t & 31);
    const int rc = t >> 5;  // 0..7, each covers 16 batch rows

    float x[16];
    float s = 0.f, s2 = 0.f;
    #pragma unroll
    for (int it = 0; it < 16; ++it) {
        const float xx = out0[(size_t)(rc * 16 + it) * DIM + f];
        x[it] = xx; s += xx; s2 += xx * xx;
    }
    ls[rc][t & 31] = s; ls2[rc][t & 31] = s2;
    __syncthreads();
    if (rc == 0) {
        float ss = 0.f, ss2 = 0.f;
        #pragma unroll
        for (int r = 0; r < 8; ++r) { ss += ls[r][t]; ss2 += ls2[r][t]; }
        const float mean = ss * (1.f / 128.f);
        const float var = ss2 * (1.f / 128.f) - mean * mean;  // biased
        const float inv = rsqrtf(var + EPS_BN);
        const float a = gamma[f] * inv;
        la[t] = a; lb[t] = beta[f] - mean * a;
    }
    __syncthreads();
    const float a = la[t & 31], bb = lb[t & 31];
    #pragma unroll
    for (int it = 0; it < 16; ++it) {
        out[(size_t)(rc * 16 + it) * DIM + f] = x[it] * a + bb;
    }
}

// ---------------------------------------------------------------------------
extern "C" void kernel_launch(void* const* d_in, const int* in_sizes, int n_in,
                              void* d_out, int out_size, void* d_ws, size_t ws_size,
                              hipStream_t stream)
{
    const float* z     = (const float*)d_in[0];
    const float* Wq    = (const float*)d_in[1];
    const float* Wk    = (const float*)d_in[2];
    const float* Wv    = (const float*)d_in[3];
    const float* gamma = (const float*)d_in[4];
    const float* beta  = (const float*)d_in[5];
    float* out = (float*)d_out;

    float* qkv  = (float*)d_ws;                       // 3 * 128 * 1024 f32
    float* out0 = qkv + (size_t)3 * BATCH * DIM;      // 128 * 1024 f32

    qkv_gemm<<<192, 256, 0, stream>>>(z, Wq, Wk, Wv, qkv);
    attn_poly<<<BATCH, 256, 0, stream>>>(qkv, out0);
    batchnorm<<<DIM / 32, 256, 0, stream>>>(out0, gamma, beta, out);
}

// Round 2
// 23.602 us; speedup vs baseline: 1.0449x; 1.0449x over previous
//
#include <hip/hip_runtime.h>
#include <hip/hip_bf16.h>
#include <stdint.h>

#define DIM 1024
#define BATCH 128
#define EPS_BN 1e-5f
#define KSPLIT 4

typedef __attribute__((ext_vector_type(8))) short bfrag;   // 8 bf16 (4 VGPRs)
typedef __attribute__((ext_vector_type(4))) float f32x4;   // MFMA accumulator

__device__ inline ushort f2bf(float f) {
    union { float f; uint32_t u; } un; un.f = f;
    uint32_t u = un.u;
    return (ushort)((u + 0x7FFFu + ((u >> 16) & 1u)) >> 16);  // RNE
}

// ---------------------------------------------------------------------------
// K1: q,k,v = z @ W.T  (three 128x1024x1024 GEMMs, N=3072), split-K=4.
// Tile BM=32, BN=64, per-block K-range=256 (4 iters of BK=64).
// Grid = 4(mt) x 48(nt) x 4(ks) = 768 blocks -> 3 blocks/CU, 12 waves/CU.
// bid = ((mt*48)+nt)*4 + ks: the 4 mt-blocks sharing a W tile differ by 192
// in bid (== 0 mod 8) -> same XCD -> W re-reads are XCD-local-L2 hits.
// ---------------------------------------------------------------------------
__global__ __launch_bounds__(256) void qkv_gemm(
    const float* __restrict__ z, const float* __restrict__ Wq,
    const float* __restrict__ Wk, const float* __restrict__ Wv,
    float* __restrict__ qkvp, int* __restrict__ sync)
{
    if (blockIdx.x == 0 && threadIdx.x == 0) *sync = 0;  // reset grid barrier

    __shared__ alignas(16) ushort As[32][72];
    __shared__ alignas(16) ushort Bs[64][72];

    const int bid = blockIdx.x;
    const int ks = bid & 3;
    const int bid2 = bid >> 2;
    const int nt = bid2 % 48, mt = bid2 / 48;
    const int m0 = mt * 32;
    const int n0 = nt * 64;
    const int w_idx = n0 >> 10;                 // which W (tile never crosses)
    const float* W = (w_idx == 0) ? Wq : (w_idx == 1) ? Wk : Wv;
    const int nrow0 = n0 & 1023;
    const int k0 = ks * 256;

    const int t = threadIdx.x;
    const int lane = t & 63, wv = t >> 6;
    const int wm = wv >> 1, wn = wv & 1;

    // staging assignments
    const int ar = t >> 3, ac = (t & 7) * 8;    // A tile [32][64]
    const int br = t >> 2, bc = (t & 3) * 16;   // B tile [64][64]
    const float* zrow = z + (size_t)(m0 + ar) * DIM + ac;
    const float* wrow = W + (size_t)(nrow0 + br) * DIM + bc;

    f32x4 acc[2] = {{0.f,0.f,0.f,0.f},{0.f,0.f,0.f,0.f}};

    for (int kk = k0; kk < k0 + 256; kk += 64) {
        // stage A: 8 f32 -> 8 bf16
        {
            float4 f0 = *(const float4*)(zrow + kk);
            float4 f1 = *(const float4*)(zrow + kk + 4);
            ushort tmp[8] = { f2bf(f0.x), f2bf(f0.y), f2bf(f0.z), f2bf(f0.w),
                              f2bf(f1.x), f2bf(f1.y), f2bf(f1.z), f2bf(f1.w) };
            *(bfrag*)&As[ar][ac] = *(bfrag*)tmp;
        }
        // stage B: 16 f32 -> 16 bf16
        {
            float4 f0 = *(const float4*)(wrow + kk);
            float4 f1 = *(const float4*)(wrow + kk + 4);
            float4 f2 = *(const float4*)(wrow + kk + 8);
            float4 f3 = *(const float4*)(wrow + kk + 12);
            ushort tmp[16] = { f2bf(f0.x), f2bf(f0.y), f2bf(f0.z), f2bf(f0.w),
                               f2bf(f1.x), f2bf(f1.y), f2bf(f1.z), f2bf(f1.w),
                               f2bf(f2.x), f2bf(f2.y), f2bf(f2.z), f2bf(f2.w),
                               f2bf(f3.x), f2bf(f3.y), f2bf(f3.z), f2bf(f3.w) };
            *(bfrag*)&Bs[br][bc]     = *(bfrag*)&tmp[0];
            *(bfrag*)&Bs[br][bc + 8] = *(bfrag*)&tmp[8];
        }
        __syncthreads();

        const int krow = (lane >> 4) * 8;  // lane-group K slot (same bijection A & B)
        #pragma unroll
        for (int mk = 0; mk < 2; ++mk) {
            bfrag af  = *(const bfrag*)&As[wm * 16      + (lane & 15)][mk * 32 + krow];
            bfrag bf0 = *(const bfrag*)&Bs[wn * 32      + (lane & 15)][mk * 32 + krow];
            bfrag bf1 = *(const bfrag*)&Bs[wn * 32 + 16 + (lane & 15)][mk * 32 + krow];
            acc[0] = __builtin_amdgcn_mfma_f32_16x16x32_bf16(af, bf0, acc[0], 0, 0, 0);
            acc[1] = __builtin_amdgcn_mfma_f32_16x16x32_bf16(af, bf1, acc[1], 0, 0, 0);
        }
        __syncthreads();
    }

    // epilogue: C/D layout: col = lane&15, row = (lane>>4)*4 + reg
    float* outbase = qkvp + (size_t)ks * (3 * BATCH * DIM)
                          + (size_t)w_idx * (BATCH * DIM);
    #pragma unroll
    for (int fn = 0; fn < 2; ++fn) {
        const int col = nrow0 + wn * 32 + fn * 16 + (lane & 15);
        #pragma unroll
        for (int r = 0; r < 4; ++r) {
            const int row = m0 + wm * 16 + (lane >> 4) * 4 + r;
            outbase[(size_t)row * DIM + col] = acc[fn][r];
        }
    }
}

// ---------------------------------------------------------------------------
// K2 (fused): combine K-partials, Taylor-moment attention, grid barrier,
// then BatchNorm tail on blocks 0..31.
// out0[b,i] = N(q_i)/S(q_i) + v_i  with
//   S(x)=sum_j exp(x*kn_j)=sum_p x^p/p! * M0_p,  N likewise with M1_p.
// ---------------------------------------------------------------------------
__global__ __launch_bounds__(256) void attn_bn(
    const float* __restrict__ qkvp, const float* __restrict__ gamma,
    const float* __restrict__ beta, float* __restrict__ out0,
    float* __restrict__ out, int* __restrict__ sync)
{
    const int b = blockIdx.x;
    const int t = threadIdx.x;
    const size_t BD = (size_t)BATCH * DIM;
    const float inv_n = 0.03125f;  // 1/sqrt(1024)

    // combine split-K partials
    float qv[4], kn[4], vv[4];
    #pragma unroll
    for (int c = 0; c < 4; ++c) {
        const int j = t + c * 256;
        float qs = 0.f, kks = 0.f, vs = 0.f;
        #pragma unroll
        for (int p = 0; p < KSPLIT; ++p) {
            const float* base = qkvp + (size_t)p * 3 * BD + (size_t)b * DIM + j;
            qs  += base[0];
            kks += base[BD];
            vs  += base[2 * BD];
        }
        qv[c] = qs; kn[c] = kks * inv_n; vv[c] = vs;
    }

    float m0[9], m1[9];
    #pragma unroll
    for (int p = 0; p < 9; ++p) { m0[p] = 0.f; m1[p] = 0.f; }
    #pragma unroll
    for (int c = 0; c < 4; ++c) {
        float pw = 1.f;
        #pragma unroll
        for (int p = 0; p < 9; ++p) { m0[p] += pw; m1[p] += pw * vv[c]; pw *= kn[c]; }
    }
    // wave reduce (64 lanes)
    #pragma unroll
    for (int p = 0; p < 9; ++p) {
        for (int off = 32; off; off >>= 1) {
            m0[p] += __shfl_xor(m0[p], off);
            m1[p] += __shfl_xor(m1[p], off);
        }
    }
    __shared__ float red0[4][9], red1[4][9];
    const int wv = t >> 6, lane = t & 63;
    if (lane == 0) {
        #pragma unroll
        for (int p = 0; p < 9; ++p) { red0[wv][p] = m0[p]; red1[wv][p] = m1[p]; }
    }
    __syncthreads();

    const float invfact[9] = {1.f, 1.f, 0.5f, 1.f/6.f, 1.f/24.f, 1.f/120.f,
                              1.f/720.f, 1.f/5040.f, 1.f/40320.f};
    float c0[9], c1[9];
    #pragma unroll
    for (int p = 0; p < 9; ++p) {
        const float s0 = red0[0][p] + red0[1][p] + red0[2][p] + red0[3][p];
        const float s1 = red1[0][p] + red1[1][p] + red1[2][p] + red1[3][p];
        c0[p] = s0 * invfact[p];
        c1[p] = s1 * invfact[p];
    }
    #pragma unroll
    for (int c = 0; c < 4; ++c) {
        const float qi = qv[c];
        float S = c0[8], N = c1[8];
        #pragma unroll
        for (int p = 7; p >= 0; --p) { S = S * qi + c0[p]; N = N * qi + c1[p]; }
        out0[(size_t)b * DIM + t + c * 256] = N / S + vv[c];
    }

    // ---- grid barrier (device-scope; 128 blocks are co-resident) ----
    __syncthreads();   // drains vmcnt -> all block stores reached L2
    if (t == 0) __hip_atomic_fetch_add(sync, 1, __ATOMIC_RELEASE,
                                       __HIP_MEMORY_SCOPE_AGENT);
    if (b >= 32) return;
    if (t == 0) {
        while (__hip_atomic_load(sync, __ATOMIC_ACQUIRE,
                                 __HIP_MEMORY_SCOPE_AGENT) < BATCH) {
            __builtin_amdgcn_s_sleep(1);
        }
    }
    __syncthreads();

    // ---- BatchNorm tail: block b handles features b*32 .. b*32+31 ----
    __shared__ float ls[8][32], ls2[8][32], la[32], lb[32];
    const int f = b * 32 + (t & 31);
    const int rc = t >> 5;  // 0..7, each covers 16 batch rows

    float x[16];
    float s = 0.f, s2 = 0.f;
    #pragma unroll
    for (int it = 0; it < 16; ++it) {
        const float xx = out0[(size_t)(rc * 16 + it) * DIM + f];
        x[it] = xx; s += xx; s2 += xx * xx;
    }
    ls[rc][t & 31] = s; ls2[rc][t & 31] = s2;
    __syncthreads();
    if (rc == 0) {
        float ss = 0.f, ss2 = 0.f;
        #pragma unroll
        for (int r = 0; r < 8; ++r) { ss += ls[r][t]; ss2 += ls2[r][t]; }
        const float mean = ss * (1.f / 128.f);
        const float var = ss2 * (1.f / 128.f) - mean * mean;  // biased
        const float inv = rsqrtf(var + EPS_BN);
        const float a = gamma[f] * inv;
        la[t] = a; lb[t] = beta[f] - mean * a;
    }
    __syncthreads();
    const float a = la[t & 31], bb = lb[t & 31];
    #pragma unroll
    for (int it = 0; it < 16; ++it) {
        out[(size_t)(rc * 16 + it) * DIM + f] = x[it] * a + bb;
    }
}

// ---------------------------------------------------------------------------
extern "C" void kernel_launch(void* const* d_in, const int* in_sizes, int n_in,
                              void* d_out, int out_size, void* d_ws, size_t ws_size,
                              hipStream_t stream)
{
    const float* z     = (const float*)d_in[0];
    const float* Wq    = (const float*)d_in[1];
    const float* Wk    = (const float*)d_in[2];
    const float* Wv    = (const float*)d_in[3];
    const float* gamma = (const float*)d_in[4];
    const float* beta  = (const float*)d_in[5];
    float* out = (float*)d_out;

    float* qkvp = (float*)d_ws;                              // 4 x 3 x 128 x 1024 f32
    float* out0 = qkvp + (size_t)KSPLIT * 3 * BATCH * DIM;   // 128 x 1024 f32
    int*   sync = (int*)(out0 + (size_t)BATCH * DIM);        // grid-barrier counter

    qkv_gemm<<<4 * 48 * KSPLIT, 256, 0, stream>>>(z, Wq, Wk, Wv, qkvp, sync);
    attn_bn<<<BATCH, 256, 0, stream>>>(qkvp, gamma, beta, out0, out, sync);
}